// Round 4
// baseline (543.836 us; speedup 1.0000x reference)
//
#include <hip/hip_runtime.h>
#include <math.h>

// Capsule routing, fused. B=64, I=1024, O=1024 fp32.
//
// Math reduction: routing state collapses to c_k = softmax_o(u*w*vsum), so
// no [B,I,O] tensor is ever materialized.
//
// R3 lesson: per-iteration wave-wide softmax reduction = 6 serial DS ops in
// the hot loop + fat live set (p[] kept across the reduce) -> 64-VGPR alloc,
// no load prefetch, ~4.8k cyc per iteration slot, VALUBusy 20%.
// R4: two-pass softmax per group of 8 i-rows. Pass A streams w and builds
// per-lane partial denominators (no cross-lane ops); ONE batched butterfly
// (16 independent chains) per group; u and q=u/d go to SGPRs via
// readfirstlane; pass B re-streams the (L1-hot) w rows and accumulates
// ar += w*exp(..)*q. Both hot loops are pure load->VALU streams.

#define BB 64
#define II 1024
#define OO 1024
#define EPSF 1e-5f
#define LOG2E 1.44269504088896340736f

__device__ __forceinline__ float wave_sum(float v) {
    #pragma unroll
    for (int off = 32; off > 0; off >>= 1)
        v += __shfl_xor(v, off, 64);
    return v;
}
__device__ __forceinline__ float rfl(float x) {  // SGPR broadcast
    return __int_as_float(__builtin_amdgcn_readfirstlane(__float_as_int(x)));
}

// Cross-wave reduce of the 4 waves' ar[16] via LDS float-atomics
// (addr/4 = k*64+lane -> 2-way aliasing, free), then coalesced float4 store.
__device__ __forceinline__ void block_reduce_store(
    float* red, const float (&ar0)[16], const float (&ar1)[16], int lane,
    float* __restrict__ part_b0, float* __restrict__ part_b1)
{
    const int t = threadIdx.x;
    for (int r = t; r < 2048; r += 256) red[r] = 0.f;
    __syncthreads();
    #pragma unroll
    for (int k = 0; k < 16; k++) {
        atomicAdd(&red[k * 64 + lane],        ar0[k]);
        atomicAdd(&red[1024 + k * 64 + lane], ar1[k]);
    }
    __syncthreads();
    const int j  = t >> 6;
    const int ln = t & 63;
    float4 v0, v1;
    v0.x = red[(j*4+0)*64 + ln]; v0.y = red[(j*4+1)*64 + ln];
    v0.z = red[(j*4+2)*64 + ln]; v0.w = red[(j*4+3)*64 + ln];
    v1.x = red[1024 + (j*4+0)*64 + ln]; v1.y = red[1024 + (j*4+1)*64 + ln];
    v1.z = red[1024 + (j*4+2)*64 + ln]; v1.w = red[1024 + (j*4+3)*64 + ln];
    ((float4*)part_b0)[t] = v0;
    ((float4*)part_b1)[t] = v1;
}

template<int IBLKS>
__global__ __launch_bounds__(256, 4) void stage_k(
    const float* __restrict__ u, const float* __restrict__ w,
    const float* __restrict__ v, float* __restrict__ part)
{
    constexpr int IPB = II / IBLKS;   // i's per block
    constexpr int IW  = IPB / 4;      // i's per wave
    constexpr int NG  = IW / 8;       // groups of 8 i's
    const int bg   = blockIdx.x / IBLKS;
    const int iblk = blockIdx.x % IBLKS;
    const int wave = threadIdx.x >> 6;
    const int lane = threadIdx.x & 63;
    const int b0 = bg * 2, b1 = b0 + 1;
    const float4* w4  = (const float4*)w;
    const float4* v40 = (const float4*)(v + b0 * OO);
    const float4* v41 = (const float4*)(v + b1 * OO);

    // lane owns o = j*256 + lane*4 + e; v pre-scaled by log2e.
    float vv0[16], vv1[16];
    #pragma unroll
    for (int j = 0; j < 4; j++) {
        float4 a = v40[j * 64 + lane];
        float4 b = v41[j * 64 + lane];
        vv0[j*4+0]=a.x*LOG2E; vv0[j*4+1]=a.y*LOG2E;
        vv0[j*4+2]=a.z*LOG2E; vv0[j*4+3]=a.w*LOG2E;
        vv1[j*4+0]=b.x*LOG2E; vv1[j*4+1]=b.y*LOG2E;
        vv1[j*4+2]=b.z*LOG2E; vv1[j*4+3]=b.w*LOG2E;
    }
    float ar0[16], ar1[16];
    #pragma unroll
    for (int k = 0; k < 16; k++) { ar0[k] = 0.f; ar1[k] = 0.f; }

    const int i0 = iblk * IPB + wave * IW;
    for (int g = 0; g < NG; g++) {
        const int ib = i0 + g * 8;

        // ---- pass A: per-lane partial denominators (no cross-lane ops) ----
        float u0[8], u1[8], sA[8], sB[8];
        #pragma unroll
        for (int ii = 0; ii < 8; ii++) {
            u0[ii] = u[b0 * II + ib + ii];
            u1[ii] = u[b1 * II + ib + ii];
            sA[ii] = 0.f; sB[ii] = 0.f;
        }
        #pragma unroll
        for (int ii = 0; ii < 8; ii++) {
            const int i = ib + ii;
            float a0 = 0.f, a1 = 0.f;
            #pragma unroll
            for (int j = 0; j < 4; j++) {
                float4 t = w4[i * 256 + j * 64 + lane];
                a0 += __builtin_amdgcn_exp2f((t.x * vv0[j*4+0]) * u0[ii])
                    + __builtin_amdgcn_exp2f((t.y * vv0[j*4+1]) * u0[ii])
                    + __builtin_amdgcn_exp2f((t.z * vv0[j*4+2]) * u0[ii])
                    + __builtin_amdgcn_exp2f((t.w * vv0[j*4+3]) * u0[ii]);
                a1 += __builtin_amdgcn_exp2f((t.x * vv1[j*4+0]) * u1[ii])
                    + __builtin_amdgcn_exp2f((t.y * vv1[j*4+1]) * u1[ii])
                    + __builtin_amdgcn_exp2f((t.z * vv1[j*4+2]) * u1[ii])
                    + __builtin_amdgcn_exp2f((t.w * vv1[j*4+3]) * u1[ii]);
            }
            sA[ii] = a0; sB[ii] = a1;
        }
        // ---- one batched butterfly: 6 layers x 16 independent chains ----
        #pragma unroll
        for (int off = 32; off > 0; off >>= 1) {
            #pragma unroll
            for (int ii = 0; ii < 8; ii++) {
                sA[ii] += __shfl_xor(sA[ii], off, 64);
                sB[ii] += __shfl_xor(sB[ii], off, 64);
            }
        }
        // u and q = u/d to SGPRs (frees VGPRs; VALU ops take 1 SGPR src)
        float us0[8], us1[8], qs0[8], qs1[8];
        #pragma unroll
        for (int ii = 0; ii < 8; ii++) {
            us0[ii] = rfl(u0[ii]);        qs0[ii] = rfl(u0[ii] / sA[ii]);
            us1[ii] = rfl(u1[ii]);        qs1[ii] = rfl(u1[ii] / sB[ii]);
        }
        // ---- pass B: re-stream (L1-hot) w rows, accumulate ----
        #pragma unroll
        for (int ii = 0; ii < 8; ii++) {
            const int i = ib + ii;
            #pragma unroll
            for (int j = 0; j < 4; j++) {
                float4 t = w4[i * 256 + j * 64 + lane];
                float p;
                p = __builtin_amdgcn_exp2f((t.x * vv0[j*4+0]) * us0[ii]);
                ar0[j*4+0] = fmaf(t.x * p, qs0[ii], ar0[j*4+0]);
                p = __builtin_amdgcn_exp2f((t.y * vv0[j*4+1]) * us0[ii]);
                ar0[j*4+1] = fmaf(t.y * p, qs0[ii], ar0[j*4+1]);
                p = __builtin_amdgcn_exp2f((t.z * vv0[j*4+2]) * us0[ii]);
                ar0[j*4+2] = fmaf(t.z * p, qs0[ii], ar0[j*4+2]);
                p = __builtin_amdgcn_exp2f((t.w * vv0[j*4+3]) * us0[ii]);
                ar0[j*4+3] = fmaf(t.w * p, qs0[ii], ar0[j*4+3]);
                p = __builtin_amdgcn_exp2f((t.x * vv1[j*4+0]) * us1[ii]);
                ar1[j*4+0] = fmaf(t.x * p, qs1[ii], ar1[j*4+0]);
                p = __builtin_amdgcn_exp2f((t.y * vv1[j*4+1]) * us1[ii]);
                ar1[j*4+1] = fmaf(t.y * p, qs1[ii], ar1[j*4+1]);
                p = __builtin_amdgcn_exp2f((t.z * vv1[j*4+2]) * us1[ii]);
                ar1[j*4+2] = fmaf(t.z * p, qs1[ii], ar1[j*4+2]);
                p = __builtin_amdgcn_exp2f((t.w * vv1[j*4+3]) * us1[ii]);
                ar1[j*4+3] = fmaf(t.w * p, qs1[ii], ar1[j*4+3]);
            }
        }
    }
    __shared__ float red[2048];
    block_reduce_store(red, ar0, ar1, lane,
        part + ((size_t)iblk * BB + b0) * OO,
        part + ((size_t)iblk * BB + b1) * OO);
}

template<int IBLKS>
__global__ __launch_bounds__(256, 4) void gemm_k(
    const float* __restrict__ u, const float* __restrict__ w,
    float* __restrict__ part)
{
    constexpr int IPB = II / IBLKS;
    constexpr int IW  = IPB / 4;
    const int bg   = blockIdx.x / IBLKS;
    const int iblk = blockIdx.x % IBLKS;
    const int wave = threadIdx.x >> 6;
    const int lane = threadIdx.x & 63;
    const int b0 = bg * 2, b1 = b0 + 1;
    const float4* w4 = (const float4*)w;

    float ar0[16], ar1[16];
    #pragma unroll
    for (int k = 0; k < 16; k++) { ar0[k] = 0.f; ar1[k] = 0.f; }

    const int i0 = iblk * IPB + wave * IW;
    #pragma unroll 2
    for (int ii = 0; ii < IW; ii++) {
        const int i = i0 + ii;
        const float ub0 = rfl(u[b0 * II + i]);
        const float ub1 = rfl(u[b1 * II + i]);
        #pragma unroll
        for (int j = 0; j < 4; j++) {
            float4 t = w4[i * 256 + j * 64 + lane];
            ar0[j*4+0] = fmaf(ub0, t.x, ar0[j*4+0]);
            ar0[j*4+1] = fmaf(ub0, t.y, ar0[j*4+1]);
            ar0[j*4+2] = fmaf(ub0, t.z, ar0[j*4+2]);
            ar0[j*4+3] = fmaf(ub0, t.w, ar0[j*4+3]);
            ar1[j*4+0] = fmaf(ub1, t.x, ar1[j*4+0]);
            ar1[j*4+1] = fmaf(ub1, t.y, ar1[j*4+1]);
            ar1[j*4+2] = fmaf(ub1, t.z, ar1[j*4+2]);
            ar1[j*4+3] = fmaf(ub1, t.w, ar1[j*4+3]);
        }
    }
    __shared__ float red[2048];
    block_reduce_store(red, ar0, ar1, lane,
        part + ((size_t)iblk * BB + b0) * OO,
        part + ((size_t)iblk * BB + b1) * OO);
}

// Sum nblk partial slices (4 independent accumulators for MLP),
// x = sum*scale + bias, squash row, emit per mode.
__global__ __launch_bounds__(256) void reduce_squash(
    const float* __restrict__ part, const float* __restrict__ bias,
    float* __restrict__ vbuf, float* __restrict__ out,
    float scale, int mode, int nblk)
{
    const int b = blockIdx.x;
    const int t = threadIdx.x;
    const float4* p4 = (const float4*)part;

    float4 a0 = make_float4(0,0,0,0), a1 = a0, a2 = a0, a3 = a0;
    for (int k = 0; k < nblk; k += 4) {
        float4 p0 = p4[(size_t)((k+0) * BB + b) * 256 + t];
        float4 p1 = p4[(size_t)((k+1) * BB + b) * 256 + t];
        float4 p2 = p4[(size_t)((k+2) * BB + b) * 256 + t];
        float4 p3 = p4[(size_t)((k+3) * BB + b) * 256 + t];
        a0.x += p0.x; a0.y += p0.y; a0.z += p0.z; a0.w += p0.w;
        a1.x += p1.x; a1.y += p1.y; a1.z += p1.z; a1.w += p1.w;
        a2.x += p2.x; a2.y += p2.y; a2.z += p2.z; a2.w += p2.w;
        a3.x += p3.x; a3.y += p3.y; a3.z += p3.z; a3.w += p3.w;
    }
    float4 a;
    a.x = (a0.x+a1.x)+(a2.x+a3.x); a.y = (a0.y+a1.y)+(a2.y+a3.y);
    a.z = (a0.z+a1.z)+(a2.z+a3.z); a.w = (a0.w+a1.w)+(a2.w+a3.w);

    float4 bb = ((const float4*)bias)[t];
    float4 x;
    x.x = fmaf(a.x, scale, bb.x); x.y = fmaf(a.y, scale, bb.y);
    x.z = fmaf(a.z, scale, bb.z); x.w = fmaf(a.w, scale, bb.w);

    float ss = x.x*x.x + x.y*x.y + x.z*x.z + x.w*x.w;
    ss = wave_sum(ss);
    __shared__ float red[4];
    if ((t & 63) == 0) red[t >> 6] = ss;
    __syncthreads();
    ss = red[0] + red[1] + red[2] + red[3];

    const float n = sqrtf(ss);
    const float f = ss / ((1.f + ss) * (n + EPSF));

    float4 vo;
    vo.x = x.x * f; vo.y = x.y * f; vo.z = x.z * f; vo.w = x.w * f;

    if (mode == 0) {
        ((float4*)(vbuf + b * OO))[t] = vo;
    } else if (mode == 1) {
        float4 pv = ((const float4*)(vbuf + b * OO))[t];
        pv.x += vo.x; pv.y += vo.y; pv.z += vo.z; pv.w += vo.w;
        ((float4*)(vbuf + b * OO))[t] = pv;
    } else {
        ((float4*)(out + b * OO))[t] = vo;
    }
}

template<int IBLKS>
static void run_pipeline(const float* u, const float* w, const float* bias,
                         float* out, void* d_ws, hipStream_t stream)
{
    float* part = (float*)d_ws;
    float* vbuf = part + (size_t)IBLKS * BB * OO;
    dim3 g((BB / 2) * IBLKS), blk(256);
    // v1 = squash((u@w)/O + bias)
    gemm_k<IBLKS><<<g, blk, 0, stream>>>(u, w, part);
    reduce_squash<<<dim3(BB), blk, 0, stream>>>(part, bias, vbuf, out,
                                                1.0f / (float)OO, 0, IBLKS);
    // vsum = v1 + squash(s2 + bias),  s2 via softmax(u*w*v1)
    stage_k<IBLKS><<<g, blk, 0, stream>>>(u, w, vbuf, part);
    reduce_squash<<<dim3(BB), blk, 0, stream>>>(part, bias, vbuf, out,
                                                1.0f, 1, IBLKS);
    // out = squash(s3 + bias),  s3 via softmax(u*w*vsum)
    stage_k<IBLKS><<<g, blk, 0, stream>>>(u, w, vbuf, part);
    reduce_squash<<<dim3(BB), blk, 0, stream>>>(part, bias, vbuf, out,
                                                1.0f, 2, IBLKS);
}

extern "C" void kernel_launch(void* const* d_in, const int* in_sizes, int n_in,
                              void* d_out, int out_size, void* d_ws, size_t ws_size,
                              hipStream_t stream) {
    (void)in_sizes; (void)n_in; (void)out_size;
    const float* u    = (const float*)d_in[0];
    const float* w    = (const float*)d_in[1];
    const float* bias = (const float*)d_in[2];
    float* out = (float*)d_out;

    const size_t row = (size_t)BB * OO * sizeof(float);  // 256 KB
    if      (ws_size >= 33 * row) run_pipeline<32>(u, w, bias, out, d_ws, stream);
    else if (ws_size >= 17 * row) run_pipeline<16>(u, w, bias, out, d_ws, stream);
    else if (ws_size >=  9 * row) run_pipeline<8>(u, w, bias, out, d_ws, stream);
    else                          run_pipeline<4>(u, w, bias, out, d_ws, stream);
}

// Round 5
// 399.081 us; speedup vs baseline: 1.3627x; 1.3627x over previous
//
#include <hip/hip_runtime.h>
#include <math.h>

// Capsule routing, fused. B=64, I=1024, O=1024 fp32.
//
// Math reduction: routing state collapses to c_k = softmax_o(u*w*vsum), so
// no [B,I,O] tensor is ever materialized.
//
// R4 lesson: BTILE=2 two-pass needed ~130 live VGPRs; allocator stayed at 64
// -> 600 MB/dispatch scratch spill traffic. R5: same two-pass structure at
// BTILE=1 (~54 live VGPRs, fits 64 clean):
//   pass A: per-lane partial softmax denominators (no cross-lane ops)
//   one batched 6-layer butterfly per 8-i group (8 chains)
//   u and q = u*rcp(d) held in SGPRs (readfirstlane)
//   pass B: re-stream the (L1-hot, 32KB) w-slice, ar += w*exp2(..)*q
// Grid BB*IBLKS = 2048 blocks = 8 blocks/CU -> 8 waves/SIMD latency hiding.

#define BB 64
#define II 1024
#define OO 1024
#define EPSF 1e-5f
#define LOG2E 1.44269504088896340736f

__device__ __forceinline__ float wave_sum(float v) {
    #pragma unroll
    for (int off = 32; off > 0; off >>= 1)
        v += __shfl_xor(v, off, 64);
    return v;
}
__device__ __forceinline__ float rfl(float x) {  // force SGPR broadcast
    return __int_as_float(__builtin_amdgcn_readfirstlane(__float_as_int(x)));
}

// Cross-wave reduce of the 4 waves' ar[16] via LDS float-atomics
// (addr/4 = k*64+lane -> 2-way aliasing, free), then coalesced float4 store.
__device__ __forceinline__ void block_reduce_store1(
    float* red, const float (&ar)[16], int lane, float* __restrict__ part_b)
{
    const int t = threadIdx.x;
    for (int r = t; r < 1024; r += 256) red[r] = 0.f;
    __syncthreads();
    #pragma unroll
    for (int k = 0; k < 16; k++)
        atomicAdd(&red[k * 64 + lane], ar[k]);
    __syncthreads();
    const int j  = t >> 6;
    const int ln = t & 63;
    float4 v0;
    v0.x = red[(j*4+0)*64 + ln]; v0.y = red[(j*4+1)*64 + ln];
    v0.z = red[(j*4+2)*64 + ln]; v0.w = red[(j*4+3)*64 + ln];
    ((float4*)part_b)[t] = v0;
}

template<int IBLKS>
__global__ __launch_bounds__(256, 4) void stage_k(
    const float* __restrict__ u, const float* __restrict__ w,
    const float* __restrict__ v, float* __restrict__ part)
{
    constexpr int IPB = II / IBLKS;   // i's per block
    constexpr int IW  = IPB / 4;      // i's per wave
    constexpr int NG  = IW / 8;       // groups of 8 i's
    static_assert(IW % 8 == 0, "need groups of 8");
    const int b    = blockIdx.x / IBLKS;
    const int iblk = blockIdx.x % IBLKS;
    const int wave = threadIdx.x >> 6;
    const int lane = threadIdx.x & 63;
    const float4* w4 = (const float4*)w;
    const float4* v4 = (const float4*)(v + b * OO);

    // lane owns o = j*256 + lane*4 + e; v pre-scaled by log2e.
    float vv[16];
    #pragma unroll
    for (int j = 0; j < 4; j++) {
        float4 a = v4[j * 64 + lane];
        vv[j*4+0]=a.x*LOG2E; vv[j*4+1]=a.y*LOG2E;
        vv[j*4+2]=a.z*LOG2E; vv[j*4+3]=a.w*LOG2E;
    }
    float ar[16];
    #pragma unroll
    for (int k = 0; k < 16; k++) ar[k] = 0.f;

    const int i0 = iblk * IPB + wave * IW;
    #pragma unroll 1
    for (int g = 0; g < NG; g++) {
        const int ib = i0 + g * 8;

        // u values -> SGPRs (wave-uniform loads)
        float us[8];
        #pragma unroll
        for (int ii = 0; ii < 8; ii++)
            us[ii] = rfl(u[b * II + ib + ii]);

        // ---- pass A: per-lane partial denominators (no cross-lane ops) ----
        float sA[8];
        #pragma unroll
        for (int ii = 0; ii < 8; ii++) {
            const int i = ib + ii;
            float a0 = 0.f;
            #pragma unroll
            for (int j = 0; j < 4; j++) {
                float4 t = w4[i * 256 + j * 64 + lane];
                a0 += __builtin_amdgcn_exp2f((t.x * vv[j*4+0]) * us[ii])
                    + __builtin_amdgcn_exp2f((t.y * vv[j*4+1]) * us[ii])
                    + __builtin_amdgcn_exp2f((t.z * vv[j*4+2]) * us[ii])
                    + __builtin_amdgcn_exp2f((t.w * vv[j*4+3]) * us[ii]);
            }
            sA[ii] = a0;
        }
        // ---- one batched butterfly: 6 layers x 8 independent chains ----
        #pragma unroll
        for (int off = 32; off > 0; off >>= 1) {
            #pragma unroll
            for (int ii = 0; ii < 8; ii++)
                sA[ii] += __shfl_xor(sA[ii], off, 64);
        }
        // q = u * rcp(d) -> SGPRs
        float qs[8];
        #pragma unroll
        for (int ii = 0; ii < 8; ii++)
            qs[ii] = rfl(us[ii] * __builtin_amdgcn_rcpf(sA[ii]));

        // ---- pass B: re-stream (L1-hot) w rows, accumulate ----
        #pragma unroll
        for (int ii = 0; ii < 8; ii++) {
            const int i = ib + ii;
            #pragma unroll
            for (int j = 0; j < 4; j++) {
                float4 t = w4[i * 256 + j * 64 + lane];
                float p;
                p = __builtin_amdgcn_exp2f((t.x * vv[j*4+0]) * us[ii]);
                ar[j*4+0] = fmaf(t.x * p, qs[ii], ar[j*4+0]);
                p = __builtin_amdgcn_exp2f((t.y * vv[j*4+1]) * us[ii]);
                ar[j*4+1] = fmaf(t.y * p, qs[ii], ar[j*4+1]);
                p = __builtin_amdgcn_exp2f((t.z * vv[j*4+2]) * us[ii]);
                ar[j*4+2] = fmaf(t.z * p, qs[ii], ar[j*4+2]);
                p = __builtin_amdgcn_exp2f((t.w * vv[j*4+3]) * us[ii]);
                ar[j*4+3] = fmaf(t.w * p, qs[ii], ar[j*4+3]);
            }
        }
    }
    __shared__ float red[1024];
    block_reduce_store1(red, ar, lane,
        part + ((size_t)iblk * BB + b) * OO);
}

// Partial GEMM slices of sum_i u*w (scale 1/O applied in squash). BTILE=2
// (live set ~45 regs: fits). Grid (BB/2)*IBLKS.
template<int IBLKS>
__global__ __launch_bounds__(256, 4) void gemm_k(
    const float* __restrict__ u, const float* __restrict__ w,
    float* __restrict__ part)
{
    constexpr int IPB = II / IBLKS;
    constexpr int IW  = IPB / 4;
    const int bg   = blockIdx.x / IBLKS;
    const int iblk = blockIdx.x % IBLKS;
    const int wave = threadIdx.x >> 6;
    const int lane = threadIdx.x & 63;
    const int b0 = bg * 2, b1 = b0 + 1;
    const float4* w4 = (const float4*)w;

    float ar0[16], ar1[16];
    #pragma unroll
    for (int k = 0; k < 16; k++) { ar0[k] = 0.f; ar1[k] = 0.f; }

    const int i0 = iblk * IPB + wave * IW;
    #pragma unroll 2
    for (int ii = 0; ii < IW; ii++) {
        const int i = i0 + ii;
        const float ub0 = rfl(u[b0 * II + i]);
        const float ub1 = rfl(u[b1 * II + i]);
        #pragma unroll
        for (int j = 0; j < 4; j++) {
            float4 t = w4[i * 256 + j * 64 + lane];
            ar0[j*4+0] = fmaf(ub0, t.x, ar0[j*4+0]);
            ar0[j*4+1] = fmaf(ub0, t.y, ar0[j*4+1]);
            ar0[j*4+2] = fmaf(ub0, t.z, ar0[j*4+2]);
            ar0[j*4+3] = fmaf(ub0, t.w, ar0[j*4+3]);
            ar1[j*4+0] = fmaf(ub1, t.x, ar1[j*4+0]);
            ar1[j*4+1] = fmaf(ub1, t.y, ar1[j*4+1]);
            ar1[j*4+2] = fmaf(ub1, t.z, ar1[j*4+2]);
            ar1[j*4+3] = fmaf(ub1, t.w, ar1[j*4+3]);
        }
    }
    __shared__ float red[2048];
    const int t = threadIdx.x;
    for (int r = t; r < 2048; r += 256) red[r] = 0.f;
    __syncthreads();
    #pragma unroll
    for (int k = 0; k < 16; k++) {
        atomicAdd(&red[k * 64 + lane],        ar0[k]);
        atomicAdd(&red[1024 + k * 64 + lane], ar1[k]);
    }
    __syncthreads();
    const int j  = t >> 6;
    const int ln = t & 63;
    float4 o0, o1;
    o0.x = red[(j*4+0)*64 + ln]; o0.y = red[(j*4+1)*64 + ln];
    o0.z = red[(j*4+2)*64 + ln]; o0.w = red[(j*4+3)*64 + ln];
    o1.x = red[1024 + (j*4+0)*64 + ln]; o1.y = red[1024 + (j*4+1)*64 + ln];
    o1.z = red[1024 + (j*4+2)*64 + ln]; o1.w = red[1024 + (j*4+3)*64 + ln];
    ((float4*)(part + ((size_t)iblk * BB + b0) * OO))[t] = o0;
    ((float4*)(part + ((size_t)iblk * BB + b1) * OO))[t] = o1;
}

// Sum nblk partial slices (4 independent accumulators),
// x = sum*scale + bias, squash row, emit per mode:
// mode 0: vbuf = v   mode 1: vbuf += v   mode 2: out = v
__global__ __launch_bounds__(256) void reduce_squash(
    const float* __restrict__ part, const float* __restrict__ bias,
    float* __restrict__ vbuf, float* __restrict__ out,
    float scale, int mode, int nblk)
{
    const int b = blockIdx.x;
    const int t = threadIdx.x;
    const float4* p4 = (const float4*)part;

    float4 a0 = make_float4(0,0,0,0), a1 = a0, a2 = a0, a3 = a0;
    for (int k = 0; k < nblk; k += 4) {
        float4 p0 = p4[(size_t)((k+0) * BB + b) * 256 + t];
        float4 p1 = p4[(size_t)((k+1) * BB + b) * 256 + t];
        float4 p2 = p4[(size_t)((k+2) * BB + b) * 256 + t];
        float4 p3 = p4[(size_t)((k+3) * BB + b) * 256 + t];
        a0.x += p0.x; a0.y += p0.y; a0.z += p0.z; a0.w += p0.w;
        a1.x += p1.x; a1.y += p1.y; a1.z += p1.z; a1.w += p1.w;
        a2.x += p2.x; a2.y += p2.y; a2.z += p2.z; a2.w += p2.w;
        a3.x += p3.x; a3.y += p3.y; a3.z += p3.z; a3.w += p3.w;
    }
    float4 a;
    a.x = (a0.x+a1.x)+(a2.x+a3.x); a.y = (a0.y+a1.y)+(a2.y+a3.y);
    a.z = (a0.z+a1.z)+(a2.z+a3.z); a.w = (a0.w+a1.w)+(a2.w+a3.w);

    float4 bb = ((const float4*)bias)[t];
    float4 x;
    x.x = fmaf(a.x, scale, bb.x); x.y = fmaf(a.y, scale, bb.y);
    x.z = fmaf(a.z, scale, bb.z); x.w = fmaf(a.w, scale, bb.w);

    float ss = x.x*x.x + x.y*x.y + x.z*x.z + x.w*x.w;
    ss = wave_sum(ss);
    __shared__ float red[4];
    if ((t & 63) == 0) red[t >> 6] = ss;
    __syncthreads();
    ss = red[0] + red[1] + red[2] + red[3];

    const float n = sqrtf(ss);
    const float f = ss / ((1.f + ss) * (n + EPSF));

    float4 vo;
    vo.x = x.x * f; vo.y = x.y * f; vo.z = x.z * f; vo.w = x.w * f;

    if (mode == 0) {
        ((float4*)(vbuf + b * OO))[t] = vo;
    } else if (mode == 1) {
        float4 pv = ((const float4*)(vbuf + b * OO))[t];
        pv.x += vo.x; pv.y += vo.y; pv.z += vo.z; pv.w += vo.w;
        ((float4*)(vbuf + b * OO))[t] = pv;
    } else {
        ((float4*)(out + b * OO))[t] = vo;
    }
}

template<int IBLKS>
static void run_pipeline(const float* u, const float* w, const float* bias,
                         float* out, void* d_ws, hipStream_t stream)
{
    float* part = (float*)d_ws;
    float* vbuf = part + (size_t)IBLKS * BB * OO;
    dim3 gs(BB * IBLKS), gg((BB / 2) * IBLKS), blk(256);
    // v1 = squash((u@w)/O + bias)
    gemm_k<IBLKS><<<gg, blk, 0, stream>>>(u, w, part);
    reduce_squash<<<dim3(BB), blk, 0, stream>>>(part, bias, vbuf, out,
                                                1.0f / (float)OO, 0, IBLKS);
    // vsum = v1 + squash(s2 + bias),  s2 via softmax(u*w*v1)
    stage_k<IBLKS><<<gs, blk, 0, stream>>>(u, w, vbuf, part);
    reduce_squash<<<dim3(BB), blk, 0, stream>>>(part, bias, vbuf, out,
                                                1.0f, 1, IBLKS);
    // out = squash(s3 + bias),  s3 via softmax(u*w*vsum)
    stage_k<IBLKS><<<gs, blk, 0, stream>>>(u, w, vbuf, part);
    reduce_squash<<<dim3(BB), blk, 0, stream>>>(part, bias, vbuf, out,
                                                1.0f, 2, IBLKS);
}

extern "C" void kernel_launch(void* const* d_in, const int* in_sizes, int n_in,
                              void* d_out, int out_size, void* d_ws, size_t ws_size,
                              hipStream_t stream) {
    (void)in_sizes; (void)n_in; (void)out_size;
    const float* u    = (const float*)d_in[0];
    const float* w    = (const float*)d_in[1];
    const float* bias = (const float*)d_in[2];
    float* out = (float*)d_out;

    const size_t row = (size_t)BB * OO * sizeof(float);  // 256 KB
    if      (ws_size >= 33 * row) run_pipeline<32>(u, w, bias, out, d_ws, stream);
    else if (ws_size >= 17 * row) run_pipeline<16>(u, w, bias, out, d_ws, stream);
    else if (ws_size >=  9 * row) run_pipeline<8>(u, w, bias, out, d_ws, stream);
    else                          run_pipeline<4>(u, w, bias, out, d_ws, stream);
}

// Round 6
// 156.291 us; speedup vs baseline: 3.4797x; 2.5535x over previous
//
#include <hip/hip_runtime.h>
#include <math.h>

// Capsule routing, fused. B=64, I=1024, O=1024 fp32.
//
// Math reduction: routing state collapses to c_k = softmax_o(u*w*vsum), so
// no [B,I,O] tensor is ever materialized.
//
// R5 lesson: compiler pins VGPR=64 (8 waves/EU heuristic) and SPILLS
// (~600B/thread scratch -> 480 MB/dispatch HBM traffic). launch_bounds'
// 2nd arg did not move it. R6:
//   * __attribute__((amdgpu_waves_per_eu(4,4))): force 4 waves/EU budget
//     (128 VGPR) -- the direct backend knob.
//   * #pragma unroll 2 on i-loops: stop the scheduler hoisting 8 iterations
//     of float4 loads (that was the transient-pressure bomb).
//   * Block = 4 waves x SAME i-range, each wave a DIFFERENT b:
//       - w addresses identical across waves -> L1 reuse x4
//       - blockIdx = bg*IBLKS + iblk -> XCD k gets iblk===k (mod 8):
//         per-XCD w set = 512 KB (L2-resident); w read from HBM ~once/stage
//       - each wave owns its (b, i-chunk) accumulator entirely -> NO LDS,
//         no barriers, direct coalesced float4 partial stores.

#define BB 64
#define II 1024
#define OO 1024
#define EPSF 1e-5f
#define LOG2E 1.44269504088896340736f

__device__ __forceinline__ float wave_sum(float v) {
    #pragma unroll
    for (int off = 32; off > 0; off >>= 1)
        v += __shfl_xor(v, off, 64);
    return v;
}
__device__ __forceinline__ float rfl(float x) {  // force SGPR broadcast
    return __int_as_float(__builtin_amdgcn_readfirstlane(__float_as_int(x)));
}

// ---------------- stage kernel ----------------
// grid = (BB/4) * IBLKS, block = 256. wave -> b = bg*4+wave.
// lane owns o = j*256 + lane*4 + e  (j,e in 0..3).
template<int IBLKS>
__global__ __launch_bounds__(256)
__attribute__((amdgpu_waves_per_eu(4, 4)))
void stage_k(
    const float* __restrict__ u, const float* __restrict__ w,
    const float* __restrict__ v, float* __restrict__ part)
{
    constexpr int IPB = II / IBLKS;   // i's per block (= per wave)
    constexpr int NG  = IPB / 8;      // groups of 8 i's
    static_assert(IPB % 8 == 0, "need groups of 8");
    const int bg   = blockIdx.x / IBLKS;
    const int iblk = blockIdx.x % IBLKS;
    const int wave = threadIdx.x >> 6;
    const int lane = threadIdx.x & 63;
    const int b    = bg * 4 + wave;
    const float4* w4 = (const float4*)w;
    const float4* v4 = (const float4*)(v + b * OO);

    // v pre-scaled by log2e so logits feed v_exp_f32 directly.
    float vv[16];
    #pragma unroll
    for (int j = 0; j < 4; j++) {
        float4 a = v4[j * 64 + lane];
        vv[j*4+0]=a.x*LOG2E; vv[j*4+1]=a.y*LOG2E;
        vv[j*4+2]=a.z*LOG2E; vv[j*4+3]=a.w*LOG2E;
    }
    float ar[16];
    #pragma unroll
    for (int k = 0; k < 16; k++) ar[k] = 0.f;

    const int i0 = iblk * IPB;
    #pragma unroll 1
    for (int g = 0; g < NG; g++) {
        const int ib = i0 + g * 8;

        // u values -> SGPRs (wave-uniform loads)
        float us[8];
        #pragma unroll
        for (int ii = 0; ii < 8; ii++)
            us[ii] = rfl(u[b * II + ib + ii]);

        // ---- pass A: per-lane partial denominators (no cross-lane ops) ----
        float sA[8];
        #pragma unroll 2
        for (int ii = 0; ii < 8; ii++) {
            const int i = ib + ii;
            float a0;
            {
                float4 t = w4[i * 256 + 0 * 64 + lane];
                a0 = __builtin_amdgcn_exp2f((t.x * vv[0]) * us[ii])
                   + __builtin_amdgcn_exp2f((t.y * vv[1]) * us[ii])
                   + __builtin_amdgcn_exp2f((t.z * vv[2]) * us[ii])
                   + __builtin_amdgcn_exp2f((t.w * vv[3]) * us[ii]);
            }
            #pragma unroll
            for (int j = 1; j < 4; j++) {
                float4 t = w4[i * 256 + j * 64 + lane];
                a0 += __builtin_amdgcn_exp2f((t.x * vv[j*4+0]) * us[ii])
                    + __builtin_amdgcn_exp2f((t.y * vv[j*4+1]) * us[ii])
                    + __builtin_amdgcn_exp2f((t.z * vv[j*4+2]) * us[ii])
                    + __builtin_amdgcn_exp2f((t.w * vv[j*4+3]) * us[ii]);
            }
            sA[ii] = a0;
        }
        // ---- one batched butterfly: 6 layers x 8 independent chains ----
        #pragma unroll
        for (int off = 32; off > 0; off >>= 1) {
            #pragma unroll
            for (int ii = 0; ii < 8; ii++)
                sA[ii] += __shfl_xor(sA[ii], off, 64);
        }
        // q = u * rcp(denom) -> SGPRs
        float qs[8];
        #pragma unroll
        for (int ii = 0; ii < 8; ii++)
            qs[ii] = rfl(us[ii] * __builtin_amdgcn_rcpf(sA[ii]));

        // ---- pass B: re-stream (L1-hot, 32KB) w rows, accumulate ----
        #pragma unroll 2
        for (int ii = 0; ii < 8; ii++) {
            const int i = ib + ii;
            #pragma unroll
            for (int j = 0; j < 4; j++) {
                float4 t = w4[i * 256 + j * 64 + lane];
                float p;
                p = __builtin_amdgcn_exp2f((t.x * vv[j*4+0]) * us[ii]);
                ar[j*4+0] = fmaf(t.x * p, qs[ii], ar[j*4+0]);
                p = __builtin_amdgcn_exp2f((t.y * vv[j*4+1]) * us[ii]);
                ar[j*4+1] = fmaf(t.y * p, qs[ii], ar[j*4+1]);
                p = __builtin_amdgcn_exp2f((t.z * vv[j*4+2]) * us[ii]);
                ar[j*4+2] = fmaf(t.z * p, qs[ii], ar[j*4+2]);
                p = __builtin_amdgcn_exp2f((t.w * vv[j*4+3]) * us[ii]);
                ar[j*4+3] = fmaf(t.w * p, qs[ii], ar[j*4+3]);
            }
        }
    }
    // direct coalesced partial store: no LDS, no barriers
    float4* dst = (float4*)(part + ((size_t)iblk * BB + b) * OO);
    #pragma unroll
    for (int j = 0; j < 4; j++) {
        float4 o;
        o.x = ar[j*4+0]; o.y = ar[j*4+1]; o.z = ar[j*4+2]; o.w = ar[j*4+3];
        dst[j * 64 + lane] = o;
    }
}

// ---------------- partial GEMM (same block structure) ----------------
template<int IBLKS>
__global__ __launch_bounds__(256)
__attribute__((amdgpu_waves_per_eu(4, 4)))
void gemm_k(
    const float* __restrict__ u, const float* __restrict__ w,
    float* __restrict__ part)
{
    constexpr int IPB = II / IBLKS;
    const int bg   = blockIdx.x / IBLKS;
    const int iblk = blockIdx.x % IBLKS;
    const int wave = threadIdx.x >> 6;
    const int lane = threadIdx.x & 63;
    const int b    = bg * 4 + wave;
    const float4* w4 = (const float4*)w;

    float ar[16];
    #pragma unroll
    for (int k = 0; k < 16; k++) ar[k] = 0.f;

    const int i0 = iblk * IPB;
    #pragma unroll 2
    for (int ii = 0; ii < IPB; ii++) {
        const int i = i0 + ii;
        const float ub = rfl(u[b * II + i]);
        #pragma unroll
        for (int j = 0; j < 4; j++) {
            float4 t = w4[i * 256 + j * 64 + lane];
            ar[j*4+0] = fmaf(ub, t.x, ar[j*4+0]);
            ar[j*4+1] = fmaf(ub, t.y, ar[j*4+1]);
            ar[j*4+2] = fmaf(ub, t.z, ar[j*4+2]);
            ar[j*4+3] = fmaf(ub, t.w, ar[j*4+3]);
        }
    }
    float4* dst = (float4*)(part + ((size_t)iblk * BB + b) * OO);
    #pragma unroll
    for (int j = 0; j < 4; j++) {
        float4 o;
        o.x = ar[j*4+0]; o.y = ar[j*4+1]; o.z = ar[j*4+2]; o.w = ar[j*4+3];
        dst[j * 64 + lane] = o;
    }
}

// Sum nblk partial slices (4 independent accumulators),
// x = sum*scale + bias, squash row, emit per mode:
// mode 0: vbuf = v   mode 1: vbuf += v   mode 2: out = v
__global__ __launch_bounds__(256) void reduce_squash(
    const float* __restrict__ part, const float* __restrict__ bias,
    float* __restrict__ vbuf, float* __restrict__ out,
    float scale, int mode, int nblk)
{
    const int b = blockIdx.x;
    const int t = threadIdx.x;
    const float4* p4 = (const float4*)part;

    float4 a0 = make_float4(0,0,0,0), a1 = a0, a2 = a0, a3 = a0;
    for (int k = 0; k < nblk; k += 4) {
        float4 p0 = p4[(size_t)((k+0) * BB + b) * 256 + t];
        float4 p1 = p4[(size_t)((k+1) * BB + b) * 256 + t];
        float4 p2 = p4[(size_t)((k+2) * BB + b) * 256 + t];
        float4 p3 = p4[(size_t)((k+3) * BB + b) * 256 + t];
        a0.x += p0.x; a0.y += p0.y; a0.z += p0.z; a0.w += p0.w;
        a1.x += p1.x; a1.y += p1.y; a1.z += p1.z; a1.w += p1.w;
        a2.x += p2.x; a2.y += p2.y; a2.z += p2.z; a2.w += p2.w;
        a3.x += p3.x; a3.y += p3.y; a3.z += p3.z; a3.w += p3.w;
    }
    float4 a;
    a.x = (a0.x+a1.x)+(a2.x+a3.x); a.y = (a0.y+a1.y)+(a2.y+a3.y);
    a.z = (a0.z+a1.z)+(a2.z+a3.z); a.w = (a0.w+a1.w)+(a2.w+a3.w);

    float4 bb = ((const float4*)bias)[t];
    float4 x;
    x.x = fmaf(a.x, scale, bb.x); x.y = fmaf(a.y, scale, bb.y);
    x.z = fmaf(a.z, scale, bb.z); x.w = fmaf(a.w, scale, bb.w);

    float ss = x.x*x.x + x.y*x.y + x.z*x.z + x.w*x.w;
    ss = wave_sum(ss);
    __shared__ float red[4];
    if ((t & 63) == 0) red[t >> 6] = ss;
    __syncthreads();
    ss = red[0] + red[1] + red[2] + red[3];

    const float n = sqrtf(ss);
    const float f = ss / ((1.f + ss) * (n + EPSF));

    float4 vo;
    vo.x = x.x * f; vo.y = x.y * f; vo.z = x.z * f; vo.w = x.w * f;

    if (mode == 0) {
        ((float4*)(vbuf + b * OO))[t] = vo;
    } else if (mode == 1) {
        float4 pv = ((const float4*)(vbuf + b * OO))[t];
        pv.x += vo.x; pv.y += vo.y; pv.z += vo.z; pv.w += vo.w;
        ((float4*)(vbuf + b * OO))[t] = pv;
    } else {
        ((float4*)(out + b * OO))[t] = vo;
    }
}

template<int IBLKS>
static void run_pipeline(const float* u, const float* w, const float* bias,
                         float* out, void* d_ws, hipStream_t stream)
{
    float* part = (float*)d_ws;
    float* vbuf = part + (size_t)IBLKS * BB * OO;
    dim3 g((BB / 4) * IBLKS), blk(256);
    // v1 = squash((u@w)/O + bias)
    gemm_k<IBLKS><<<g, blk, 0, stream>>>(u, w, part);
    reduce_squash<<<dim3(BB), blk, 0, stream>>>(part, bias, vbuf, out,
                                                1.0f / (float)OO, 0, IBLKS);
    // vsum = v1 + squash(s2 + bias),  s2 via softmax(u*w*v1)
    stage_k<IBLKS><<<g, blk, 0, stream>>>(u, w, vbuf, part);
    reduce_squash<<<dim3(BB), blk, 0, stream>>>(part, bias, vbuf, out,
                                                1.0f, 1, IBLKS);
    // out = squash(s3 + bias),  s3 via softmax(u*w*vsum)
    stage_k<IBLKS><<<g, blk, 0, stream>>>(u, w, vbuf, part);
    reduce_squash<<<dim3(BB), blk, 0, stream>>>(part, bias, vbuf, out,
                                                1.0f, 2, IBLKS);
}

extern "C" void kernel_launch(void* const* d_in, const int* in_sizes, int n_in,
                              void* d_out, int out_size, void* d_ws, size_t ws_size,
                              hipStream_t stream) {
    (void)in_sizes; (void)n_in; (void)out_size;
    const float* u    = (const float*)d_in[0];
    const float* w    = (const float*)d_in[1];
    const float* bias = (const float*)d_in[2];
    float* out = (float*)d_out;

    const size_t row = (size_t)BB * OO * sizeof(float);  // 256 KB
    if      (ws_size >= 65 * row) run_pipeline<64>(u, w, bias, out, d_ws, stream);
    else if (ws_size >= 33 * row) run_pipeline<32>(u, w, bias, out, d_ws, stream);
    else if (ws_size >= 17 * row) run_pipeline<16>(u, w, bias, out, d_ws, stream);
    else                          run_pipeline<8>(u, w, bias, out, d_ws, stream);
}

// Round 7
// 148.652 us; speedup vs baseline: 3.6585x; 1.0514x over previous
//
#include <hip/hip_runtime.h>
#include <math.h>

// Capsule routing, fused. B=64, I=1024, O=1024 fp32.
//
// Math reduction: routing state collapses to c_k = softmax_o(u*w*vsum), so
// no [B,I,O] tensor is ever materialized.
//
// R6 (current equilibrium): stage_k/gemm_k spill-free at VGPR<=128 via
// amdgpu_waves_per_eu(4,4) + unroll 2; block = 4 waves x same i-range,
// wave owns b -> w shared through L1, XCD-local w slices in L2, no LDS in
// the hot kernels, direct coalesced partial stores.
// R7: reduce_squash was 64 serial float4 loads/thread on 64 blocks ->
// latency chain. Now 1024 thr/block: thread (sl,qd) sums nblk/4 slices,
// 16KB LDS float4 tree, squash epilogue on threads<256.

#define BB 64
#define II 1024
#define OO 1024
#define EPSF 1e-5f
#define LOG2E 1.44269504088896340736f

__device__ __forceinline__ float wave_sum(float v) {
    #pragma unroll
    for (int off = 32; off > 0; off >>= 1)
        v += __shfl_xor(v, off, 64);
    return v;
}
__device__ __forceinline__ float rfl(float x) {  // force SGPR broadcast
    return __int_as_float(__builtin_amdgcn_readfirstlane(__float_as_int(x)));
}

// ---------------- stage kernel ----------------
// grid = (BB/4) * IBLKS, block = 256. wave -> b = bg*4+wave.
// lane owns o = j*256 + lane*4 + e  (j,e in 0..3).
template<int IBLKS>
__global__ __launch_bounds__(256)
__attribute__((amdgpu_waves_per_eu(4, 4)))
void stage_k(
    const float* __restrict__ u, const float* __restrict__ w,
    const float* __restrict__ v, float* __restrict__ part)
{
    constexpr int IPB = II / IBLKS;   // i's per block (= per wave)
    constexpr int NG  = IPB / 8;      // groups of 8 i's
    static_assert(IPB % 8 == 0, "need groups of 8");
    const int bg   = blockIdx.x / IBLKS;
    const int iblk = blockIdx.x % IBLKS;
    const int wave = threadIdx.x >> 6;
    const int lane = threadIdx.x & 63;
    const int b    = bg * 4 + wave;
    const float4* w4 = (const float4*)w;
    const float4* v4 = (const float4*)(v + b * OO);

    // v pre-scaled by log2e so logits feed v_exp_f32 directly.
    float vv[16];
    #pragma unroll
    for (int j = 0; j < 4; j++) {
        float4 a = v4[j * 64 + lane];
        vv[j*4+0]=a.x*LOG2E; vv[j*4+1]=a.y*LOG2E;
        vv[j*4+2]=a.z*LOG2E; vv[j*4+3]=a.w*LOG2E;
    }
    float ar[16];
    #pragma unroll
    for (int k = 0; k < 16; k++) ar[k] = 0.f;

    const int i0 = iblk * IPB;
    #pragma unroll 1
    for (int g = 0; g < NG; g++) {
        const int ib = i0 + g * 8;

        // u values -> SGPRs (wave-uniform loads)
        float us[8];
        #pragma unroll
        for (int ii = 0; ii < 8; ii++)
            us[ii] = rfl(u[b * II + ib + ii]);

        // ---- pass A: per-lane partial denominators (no cross-lane ops) ----
        float sA[8];
        #pragma unroll 2
        for (int ii = 0; ii < 8; ii++) {
            const int i = ib + ii;
            float a0;
            {
                float4 t = w4[i * 256 + 0 * 64 + lane];
                a0 = __builtin_amdgcn_exp2f((t.x * vv[0]) * us[ii])
                   + __builtin_amdgcn_exp2f((t.y * vv[1]) * us[ii])
                   + __builtin_amdgcn_exp2f((t.z * vv[2]) * us[ii])
                   + __builtin_amdgcn_exp2f((t.w * vv[3]) * us[ii]);
            }
            #pragma unroll
            for (int j = 1; j < 4; j++) {
                float4 t = w4[i * 256 + j * 64 + lane];
                a0 += __builtin_amdgcn_exp2f((t.x * vv[j*4+0]) * us[ii])
                    + __builtin_amdgcn_exp2f((t.y * vv[j*4+1]) * us[ii])
                    + __builtin_amdgcn_exp2f((t.z * vv[j*4+2]) * us[ii])
                    + __builtin_amdgcn_exp2f((t.w * vv[j*4+3]) * us[ii]);
            }
            sA[ii] = a0;
        }
        // ---- one batched butterfly: 6 layers x 8 independent chains ----
        #pragma unroll
        for (int off = 32; off > 0; off >>= 1) {
            #pragma unroll
            for (int ii = 0; ii < 8; ii++)
                sA[ii] += __shfl_xor(sA[ii], off, 64);
        }
        // q = u * rcp(denom) -> SGPRs
        float qs[8];
        #pragma unroll
        for (int ii = 0; ii < 8; ii++)
            qs[ii] = rfl(us[ii] * __builtin_amdgcn_rcpf(sA[ii]));

        // ---- pass B: re-stream (L1-hot, 32KB) w rows, accumulate ----
        #pragma unroll 2
        for (int ii = 0; ii < 8; ii++) {
            const int i = ib + ii;
            #pragma unroll
            for (int j = 0; j < 4; j++) {
                float4 t = w4[i * 256 + j * 64 + lane];
                float p;
                p = __builtin_amdgcn_exp2f((t.x * vv[j*4+0]) * us[ii]);
                ar[j*4+0] = fmaf(t.x * p, qs[ii], ar[j*4+0]);
                p = __builtin_amdgcn_exp2f((t.y * vv[j*4+1]) * us[ii]);
                ar[j*4+1] = fmaf(t.y * p, qs[ii], ar[j*4+1]);
                p = __builtin_amdgcn_exp2f((t.z * vv[j*4+2]) * us[ii]);
                ar[j*4+2] = fmaf(t.z * p, qs[ii], ar[j*4+2]);
                p = __builtin_amdgcn_exp2f((t.w * vv[j*4+3]) * us[ii]);
                ar[j*4+3] = fmaf(t.w * p, qs[ii], ar[j*4+3]);
            }
        }
    }
    // direct coalesced partial store: no LDS, no barriers
    float4* dst = (float4*)(part + ((size_t)iblk * BB + b) * OO);
    #pragma unroll
    for (int j = 0; j < 4; j++) {
        float4 o;
        o.x = ar[j*4+0]; o.y = ar[j*4+1]; o.z = ar[j*4+2]; o.w = ar[j*4+3];
        dst[j * 64 + lane] = o;
    }
}

// ---------------- partial GEMM (same block structure) ----------------
template<int IBLKS>
__global__ __launch_bounds__(256)
__attribute__((amdgpu_waves_per_eu(4, 4)))
void gemm_k(
    const float* __restrict__ u, const float* __restrict__ w,
    float* __restrict__ part)
{
    constexpr int IPB = II / IBLKS;
    const int bg   = blockIdx.x / IBLKS;
    const int iblk = blockIdx.x % IBLKS;
    const int wave = threadIdx.x >> 6;
    const int lane = threadIdx.x & 63;
    const int b    = bg * 4 + wave;
    const float4* w4 = (const float4*)w;

    float ar[16];
    #pragma unroll
    for (int k = 0; k < 16; k++) ar[k] = 0.f;

    const int i0 = iblk * IPB;
    #pragma unroll 2
    for (int ii = 0; ii < IPB; ii++) {
        const int i = i0 + ii;
        const float ub = rfl(u[b * II + i]);
        #pragma unroll
        for (int j = 0; j < 4; j++) {
            float4 t = w4[i * 256 + j * 64 + lane];
            ar[j*4+0] = fmaf(ub, t.x, ar[j*4+0]);
            ar[j*4+1] = fmaf(ub, t.y, ar[j*4+1]);
            ar[j*4+2] = fmaf(ub, t.z, ar[j*4+2]);
            ar[j*4+3] = fmaf(ub, t.w, ar[j*4+3]);
        }
    }
    float4* dst = (float4*)(part + ((size_t)iblk * BB + b) * OO);
    #pragma unroll
    for (int j = 0; j < 4; j++) {
        float4 o;
        o.x = ar[j*4+0]; o.y = ar[j*4+1]; o.z = ar[j*4+2]; o.w = ar[j*4+3];
        dst[j * 64 + lane] = o;
    }
}

// ---------------- reduce + squash ----------------
// 1024 threads: thread (sl = t>>8, qd = t&255) sums slices
// [sl*nblk/4, (sl+1)*nblk/4) of o-quad qd; 16KB LDS float4 tree; squash
// epilogue on threads<256. mode 0: vbuf=v  1: vbuf+=v  2: out=v
__global__ __launch_bounds__(1024) void reduce_squash(
    const float* __restrict__ part, const float* __restrict__ bias,
    float* __restrict__ vbuf, float* __restrict__ out,
    float scale, int mode, int nblk)
{
    const int b  = blockIdx.x;
    const int t  = threadIdx.x;
    const int qd = t & 255;
    const int sl = t >> 8;
    const int per = nblk >> 2;
    const float4* p4 = (const float4*)part;

    float4 a0 = make_float4(0.f, 0.f, 0.f, 0.f), a1 = a0;
    const int k0 = sl * per;
    #pragma unroll 2
    for (int k = 0; k < per; k += 2) {
        float4 p0 = p4[(size_t)((k0 + k)     * BB + b) * 256 + qd];
        float4 p1 = p4[(size_t)((k0 + k + 1) * BB + b) * 256 + qd];
        a0.x += p0.x; a0.y += p0.y; a0.z += p0.z; a0.w += p0.w;
        a1.x += p1.x; a1.y += p1.y; a1.z += p1.z; a1.w += p1.w;
    }
    a0.x += a1.x; a0.y += a1.y; a0.z += a1.z; a0.w += a1.w;

    __shared__ float4 redq[1024];   // [sl][qd], 16 KB
    redq[t] = a0;
    __syncthreads();

    float ss = 0.f;
    float4 x;
    if (t < 256) {
        float4 r0 = redq[qd], r1 = redq[256 + qd],
               r2 = redq[512 + qd], r3 = redq[768 + qd];
        float4 s;
        s.x = (r0.x + r1.x) + (r2.x + r3.x);
        s.y = (r0.y + r1.y) + (r2.y + r3.y);
        s.z = (r0.z + r1.z) + (r2.z + r3.z);
        s.w = (r0.w + r1.w) + (r2.w + r3.w);
        float4 bb = ((const float4*)bias)[qd];
        x.x = fmaf(s.x, scale, bb.x); x.y = fmaf(s.y, scale, bb.y);
        x.z = fmaf(s.z, scale, bb.z); x.w = fmaf(s.w, scale, bb.w);
        ss = x.x*x.x + x.y*x.y + x.z*x.z + x.w*x.w;
    }
    ss = wave_sum(ss);              // waves 4..15 carry zeros
    __shared__ float red2[16];
    if ((t & 63) == 0) red2[t >> 6] = ss;
    __syncthreads();
    const float tot = (red2[0] + red2[1]) + (red2[2] + red2[3]);

    if (t < 256) {
        const float n = sqrtf(tot);
        const float f = tot / ((1.f + tot) * (n + EPSF));
        float4 vo;
        vo.x = x.x * f; vo.y = x.y * f; vo.z = x.z * f; vo.w = x.w * f;
        if (mode == 0) {
            ((float4*)(vbuf + b * OO))[qd] = vo;
        } else if (mode == 1) {
            float4 pv = ((const float4*)(vbuf + b * OO))[qd];
            pv.x += vo.x; pv.y += vo.y; pv.z += vo.z; pv.w += vo.w;
            ((float4*)(vbuf + b * OO))[qd] = pv;
        } else {
            ((float4*)(out + b * OO))[qd] = vo;
        }
    }
}

template<int IBLKS>
static void run_pipeline(const float* u, const float* w, const float* bias,
                         float* out, void* d_ws, hipStream_t stream)
{
    float* part = (float*)d_ws;
    float* vbuf = part + (size_t)IBLKS * BB * OO;
    dim3 g((BB / 4) * IBLKS), blk(256), rblk(1024);
    // v1 = squash((u@w)/O + bias)
    gemm_k<IBLKS><<<g, blk, 0, stream>>>(u, w, part);
    reduce_squash<<<dim3(BB), rblk, 0, stream>>>(part, bias, vbuf, out,
                                                 1.0f / (float)OO, 0, IBLKS);
    // vsum = v1 + squash(s2 + bias),  s2 via softmax(u*w*v1)
    stage_k<IBLKS><<<g, blk, 0, stream>>>(u, w, vbuf, part);
    reduce_squash<<<dim3(BB), rblk, 0, stream>>>(part, bias, vbuf, out,
                                                 1.0f, 1, IBLKS);
    // out = squash(s3 + bias),  s3 via softmax(u*w*vsum)
    stage_k<IBLKS><<<g, blk, 0, stream>>>(u, w, vbuf, part);
    reduce_squash<<<dim3(BB), rblk, 0, stream>>>(part, bias, vbuf, out,
                                                 1.0f, 2, IBLKS);
}

extern "C" void kernel_launch(void* const* d_in, const int* in_sizes, int n_in,
                              void* d_out, int out_size, void* d_ws, size_t ws_size,
                              hipStream_t stream) {
    (void)in_sizes; (void)n_in; (void)out_size;
    const float* u    = (const float*)d_in[0];
    const float* w    = (const float*)d_in[1];
    const float* bias = (const float*)d_in[2];
    float* out = (float*)d_out;

    const size_t row = (size_t)BB * OO * sizeof(float);  // 256 KB
    if      (ws_size >= 65 * row) run_pipeline<64>(u, w, bias, out, d_ws, stream);
    else if (ws_size >= 33 * row) run_pipeline<32>(u, w, bias, out, d_ws, stream);
    else if (ws_size >= 17 * row) run_pipeline<16>(u, w, bias, out, d_ws, stream);
    else                          run_pipeline<8>(u, w, bias, out, d_ws, stream);
}